// Round 11
// baseline (105.214 us; speedup 1.0000x reference)
//
#include <hip/hip_runtime.h>
#include <math.h>

#define BATCH 4
#define NSEQ  1280
#define CDIM  512
#define HEADS 8
#define HD    64
#define NT    20     // 1280/64 k-tiles
#define NQT   20     // 1280/64 q-tiles (QB=64)

typedef __attribute__((ext_vector_type(8))) short bf16x8;
typedef __attribute__((ext_vector_type(4))) float f32x4;
typedef __attribute__((ext_vector_type(4))) unsigned short us4;

#define MFMA16(a,b,c) __builtin_amdgcn_mfma_f32_16x16x32_bf16(a,b,c,0,0,0)

__device__ __forceinline__ unsigned short f2bf(float f) {
    union { float f; unsigned int u; } v; v.f = f;
    unsigned int r = v.u + 0x7fffu + ((v.u >> 16) & 1u);   // RNE
    return (unsigned short)(r >> 16);
}
__device__ __forceinline__ float bf2f(unsigned short h) {
    union { unsigned int u; float f; } v; v.u = ((unsigned int)h) << 16;
    return v.f;
}
__device__ __forceinline__ void gload_lds16(const void* g, void* l) {
    __builtin_amdgcn_global_load_lds(
        (const __attribute__((address_space(1))) unsigned int*)g,
        (__attribute__((address_space(3))) unsigned int*)l, 16, 0, 0);
}

// ---------------------------------------------------------------------------
// conv: x f32 -> xb bf16 (5120 x 512, gemm-A swizzled)
//       W_qkv/W_proj f32 -> transposed bf16 (N x 512, gemm-B swizzled)
//       Q-columns of W_qkv (n<512) pre-scaled by 0.125 (folds attn scale)
// ---------------------------------------------------------------------------
__global__ __launch_bounds__(256)
void conv_kernel(const float* __restrict__ x, const float* __restrict__ Wq,
                 const float* __restrict__ Wp, unsigned short* __restrict__ xb,
                 unsigned short* __restrict__ Wqt, unsigned short* __restrict__ Wpt)
{
    __shared__ float lt[64][65];
    const int bx = blockIdx.x;
    const int tid = threadIdx.x;
    if (bx < 1280) {
        const int u = bx * 256 + tid;      // 5120 rows x 64 8-blocks
        const int m = u >> 6;
        const int b6 = u & 63;
        const int chunk = b6 >> 3;         // 64-elem K-chunk 0..7
        const int blk = b6 & 7;
        const float* src = x + (size_t)m * 512 + b6 * 8;
        bf16x8 hv;
        #pragma unroll
        for (int j = 0; j < 8; ++j) hv[j] = (short)f2bf(src[j]);
        *(bf16x8*)(xb + (size_t)m * 512 + chunk * 64 + ((blk ^ (m & 7)) * 8)) = hv;
    } else {
        int wi = bx - 1280;
        const float* W; unsigned short* Wt; int N, kt, nt; bool isQ;
        if (wi < 192) { W = Wq; Wt = Wqt; N = 1536; kt = wi / 24; nt = wi % 24; isQ = true; }
        else { wi -= 192; W = Wp; Wt = Wpt; N = 512; kt = wi / 8; nt = wi % 8; isQ = false; }
        const int k0 = kt * 64, n0 = nt * 64;
        {
            const int r = tid >> 4;
            const int c = (tid & 15) * 4;
            #pragma unroll
            for (int i = 0; i < 4; ++i) {
                const float4 v = *(const float4*)(W + (size_t)(k0 + r + i * 16) * N + n0 + c);
                lt[r + i * 16][c + 0] = v.x; lt[r + i * 16][c + 1] = v.y;
                lt[r + i * 16][c + 2] = v.z; lt[r + i * 16][c + 3] = v.w;
            }
        }
        __syncthreads();
        #pragma unroll
        for (int i = 0; i < 2; ++i) {
            const int u = tid + i * 256;
            const int n = u >> 3;
            const int blk = u & 7;
            const int kin = (blk ^ (n & 7)) * 8;
            const float sc = (isQ && (n0 + n) < 512) ? 0.125f : 1.0f;
            bf16x8 o;
            #pragma unroll
            for (int j = 0; j < 8; ++j) o[j] = (short)f2bf(lt[kin + j][n] * sc);
            *(bf16x8*)(Wt + (size_t)(n0 + n) * 512 + k0 + blk * 8) = o;
        }
    }
}

// ---------------------------------------------------------------------------
// bf16 MFMA GEMM: C(MxN) = A(M x 512, swz) @ B(N x 512, swz)^T
// 1D grid + XCD-chunked swizzle. SPLITV: n0>=1024 blocks (V columns) write
// C^T to Vtf[d][m] via padded-LDS transpose; n0<1024 writes qkb stride CN.
// Non-SPLITV f32 epilogue uses non-temporal stores (final output).
// ---------------------------------------------------------------------------
template<int WM, int WN, bool BIAS, bool OUTBF16, bool SPLITV>
__global__ __launch_bounds__(256)
void gemm_bf16(const unsigned short* __restrict__ A,
               const unsigned short* __restrict__ B,
               const float* __restrict__ bias, void* __restrict__ Cv,
               unsigned short* __restrict__ Vtf,
               int M, int N, int KA, int CN)
{
    constexpr int BM = 2 * WM, BN = 2 * WN;
    constexpr int MI = WM / 16, NI = WN / 16;
    constexpr int SM0 = (BM + BN) * 64;
    constexpr int SM1 = SPLITV ? BN * (BM + 8) : 0;
    __shared__ __align__(16) unsigned short smem[SM0 > SM1 ? SM0 : SM1];
    unsigned short* As = smem;
    unsigned short* Bs = smem + BM * 64;

    const int tid = threadIdx.x;
    const int w = tid >> 6, lane = tid & 63;
    const int l15 = lane & 15, hi = lane >> 4;
    const int wr = w >> 1, wc = w & 1;

    // XCD-chunked bijective swizzle (grid %8 == 0)
    const int nb = gridDim.x;
    const int L = (blockIdx.x & 7) * (nb >> 3) + (blockIdx.x >> 3);
    const int nx = N / BN;
    const int m0 = (L / nx) * BM, n0 = (L % nx) * BN;

    f32x4 acc[MI][NI];
    #pragma unroll
    for (int mi = 0; mi < MI; ++mi)
        #pragma unroll
        for (int ni = 0; ni < NI; ++ni) acc[mi][ni] = (f32x4){0.f, 0.f, 0.f, 0.f};

    constexpr int LA = BM * 128 / 4096;
    constexpr int LB = BN * 128 / 4096;

    for (int k0 = 0; k0 < KA; k0 += 64) {
        #pragma unroll
        for (int i = 0; i < LA; ++i) {
            const int off = tid * 16 + i * 4096;
            const int row = off >> 7, cb = off & 127;
            gload_lds16((const char*)A + ((size_t)(m0 + row) * KA + k0) * 2 + cb,
                        (char*)As + off);
        }
        #pragma unroll
        for (int i = 0; i < LB; ++i) {
            const int off = tid * 16 + i * 4096;
            const int row = off >> 7, cb = off & 127;
            gload_lds16((const char*)B + ((size_t)(n0 + row) * 512 + k0) * 2 + cb,
                        (char*)Bs + off);
        }
        __syncthreads();
        #pragma unroll
        for (int kk = 0; kk < 2; ++kk) {
            bf16x8 af[MI], bfr[NI];
            #pragma unroll
            for (int mi = 0; mi < MI; ++mi) {
                const int row = wr * WM + mi * 16 + l15;
                af[mi] = *(const bf16x8*)(As + row * 64 + ((kk * 4 + hi) ^ (row & 7)) * 8);
            }
            #pragma unroll
            for (int ni = 0; ni < NI; ++ni) {
                const int row = wc * WN + ni * 16 + l15;
                bfr[ni] = *(const bf16x8*)(Bs + row * 64 + ((kk * 4 + hi) ^ (row & 7)) * 8);
            }
            #pragma unroll
            for (int mi = 0; mi < MI; ++mi)
                #pragma unroll
                for (int ni = 0; ni < NI; ++ni)
                    acc[mi][ni] = MFMA16(af[mi], bfr[ni], acc[mi][ni]);
        }
        __syncthreads();
    }

    if (SPLITV && n0 >= 1024) {
        // V columns: write C^T (bf16) -> Vtf[d = n0-1024+col][m0+row], linear
        #pragma unroll
        for (int mi = 0; mi < MI; ++mi)
            #pragma unroll
            for (int ni = 0; ni < NI; ++ni) {
                us4 tv;
                tv[0] = f2bf(acc[mi][ni][0]); tv[1] = f2bf(acc[mi][ni][1]);
                tv[2] = f2bf(acc[mi][ni][2]); tv[3] = f2bf(acc[mi][ni][3]);
                const int col = wc * WN + ni * 16 + l15;
                *(us4*)&smem[col * (BM + 8) + wr * WM + mi * 16 + hi * 4] = tv;
            }
        __syncthreads();
        constexpr int UNITS2 = BN * (BM / 8) / 256;
        #pragma unroll
        for (int i = 0; i < UNITS2; ++i) {
            const int u = tid + i * 256;
            const int srow = u / (BM / 8), cu = u % (BM / 8);
            *(bf16x8*)(Vtf + (size_t)(n0 - 1024 + srow) * 5120 + m0 + cu * 8) =
                *(const bf16x8*)&smem[srow * (BM + 8) + cu * 8];
        }
    } else if (OUTBF16) {
        unsigned short* C = (unsigned short*)Cv;
        #pragma unroll
        for (int mi = 0; mi < MI; ++mi)
            #pragma unroll
            for (int ni = 0; ni < NI; ++ni)
                #pragma unroll
                for (int r = 0; r < 4; ++r)
                    smem[(wr * WM + mi * 16 + hi * 4 + r) * BN + wc * WN + ni * 16 + l15] =
                        f2bf(acc[mi][ni][r]);
        __syncthreads();
        constexpr int UNITS = BM * BN / 8 / 256;
        #pragma unroll
        for (int i = 0; i < UNITS; ++i) {
            const int u = tid + i * 256;
            const int row = u / (BN / 8), cb = u % (BN / 8);
            *(bf16x8*)(C + (size_t)(m0 + row) * CN + n0 + cb * 8) =
                *(const bf16x8*)(smem + row * BN + cb * 8);
        }
    } else {
        float* C = (float*)Cv;
        #pragma unroll
        for (int mi = 0; mi < MI; ++mi)
            #pragma unroll
            for (int ni = 0; ni < NI; ++ni) {
                const int col = n0 + wc * WN + ni * 16 + l15;
                const float bv = BIAS ? bias[col] : 0.f;
                #pragma unroll
                for (int r = 0; r < 4; ++r)
                    __builtin_nontemporal_store(
                        acc[mi][ni][r] + bv,
                        &C[(size_t)(m0 + wr * WM + mi * 16 + hi * 4 + r) * CN + col]);
            }
    }
}

// ---------------------------------------------------------------------------
// Two-pass MFMA attention, QB=64, Q/K from qkb (5120x1024), V from Vtf.
// This round: (1) attn stores non-temporal (write-once stream; keep L2 for
// K/V), (2) psh = XOR-swizzled flat 8KB -> LDS exactly 40960B = 4 blocks/CU.
// outh's global XOR absorbed into psh swizzle (n&7 == rowL&7).
// XCD swizzle: bh = bx % 32 -> all 20 q-tiles of a (b,h) share one XCD L2.
// ---------------------------------------------------------------------------
__global__ __launch_bounds__(256)
void attn_mfma(const unsigned short* __restrict__ qkb,
               const unsigned short* __restrict__ Vtf,
               const int* __restrict__ mask,
               float* __restrict__ attn, unsigned short* __restrict__ outh)
{
    __shared__ __align__(16) unsigned short kbuf[2][4096];
    __shared__ __align__(16) unsigned short vbuf[2][4096];
    __shared__ __align__(16) unsigned short psh[4096];   // 64x64 bf16, XOR-swizzled

    const int bx = blockIdx.x;
    const int bh = bx & 31;           // XCD = bh % 8
    const int qt = bx >> 5;
    const int b = bh >> 3, h = bh & 7;
    const int tid = threadIdx.x;
    const int w = tid >> 6;
    const int lane = tid & 63;
    const int l15 = lane & 15;
    const int hi = lane >> 4;
    const int q0 = qt * 64;

    unsigned int amask = 0xF0000u;
    #pragma unroll
    for (int g = 0; g < 4; ++g)
        if (mask[b * 4 + g] != 0) amask |= (0xFu << (g * 4));

    // Q fragments directly from qkb (pre-scaled by 1/8 via Wqt)
    const unsigned short* qrow =
        qkb + (size_t)(b * NSEQ + q0 + w * 16 + l15) * 1024 + h * HD;
    const bf16x8 aq0 = *(const bf16x8*)(qrow + hi * 8);
    const bf16x8 aq1 = *(const bf16x8*)(qrow + 32 + hi * 8);

    const unsigned short* ks = qkb + (size_t)b * NSEQ * 1024 + 512 + h * HD;
    const unsigned short* vg = Vtf + (size_t)h * HD * 5120 + b * NSEQ;

    // stage K tile t (source-swizzled rows of qkb) / V tile t (source-swz Vtf)
    #define STAGE_K(t, buf)                                                      \
        { _Pragma("unroll")                                                      \
          for (int half_ = 0; half_ < 2; ++half_) {                              \
            const int idx_ = half_ * 256 + tid;                                  \
            const int row_ = idx_ >> 3, blk_ = idx_ & 7;                         \
            gload_lds16(ks + (size_t)((t) * 64 + row_) * 1024                    \
                           + ((blk_ ^ (row_ & 7)) * 8),                          \
                        (char*)&(buf)[0] + idx_ * 16); } }
    #define STAGE_V(t, buf)                                                      \
        { _Pragma("unroll")                                                      \
          for (int half_ = 0; half_ < 2; ++half_) {                              \
            const int idx_ = half_ * 256 + tid;                                  \
            const int row_ = idx_ >> 3, blk_ = idx_ & 7;                         \
            gload_lds16(vg + (size_t)row_ * 5120 + (t) * 64                      \
                           + ((blk_ ^ (row_ & 7)) * 8),                          \
                        (char*)&(buf)[0] + idx_ * 16); } }

    float lr[4] = {0.f, 0.f, 0.f, 0.f};

    int t0 = 0;
    while (!((amask >> t0) & 1u)) ++t0;

    // ---------------- pass 1: exp-sums (fixed max = 0) ----------------
    STAGE_K(t0, kbuf[0]);
    __syncthreads();
    int cur = 0, t = t0;
    while (t < NT) {
        int tn = t + 1;
        while (tn < NT && !((amask >> tn) & 1u)) ++tn;
        if (tn < NT) STAGE_K(tn, kbuf[cur ^ 1]);
        f32x4 accS[4];
        #pragma unroll
        for (int cb = 0; cb < 4; ++cb) accS[cb] = (f32x4){0.f, 0.f, 0.f, 0.f};
        #pragma unroll
        for (int cb = 0; cb < 4; ++cb) {
            const int row = cb * 16 + l15;
            const char* bp = (const char*)&kbuf[cur][0] + row * 128;
            const bf16x8 b0 = *(const bf16x8*)(bp + ((hi ^ (row & 7)) * 16));
            const bf16x8 b1 = *(const bf16x8*)(bp + (((4 + hi) ^ (row & 7)) * 16));
            accS[cb] = MFMA16(aq0, b0, accS[cb]);
            accS[cb] = MFMA16(aq1, b1, accS[cb]);
        }
        #pragma unroll
        for (int cb = 0; cb < 4; ++cb)
            #pragma unroll
            for (int r = 0; r < 4; ++r)
                lr[r] += __expf(accS[cb][r]);
        __syncthreads();
        cur ^= 1; t = tn;
    }

    float rl[4];
    #pragma unroll
    for (int r = 0; r < 4; ++r) {
        float s = lr[r];
        s += __shfl_xor(s, 1);
        s += __shfl_xor(s, 2);
        s += __shfl_xor(s, 4);
        s += __shfl_xor(s, 8);
        rl[r] = 1.f / s;
    }

    // zero-fill masked tiles of attn (non-temporal)
    {
        float* arow = attn + ((size_t)bh * NSEQ + q0 + w * 16) * NSEQ;
        const f32x4 z = (f32x4){0.f, 0.f, 0.f, 0.f};
        for (int tz = 0; tz < NT; ++tz) {
            if ((amask >> tz) & 1u) continue;
            #pragma unroll
            for (int rr = 0; rr < 4; ++rr)
                __builtin_nontemporal_store(
                    z, (f32x4*)(arow + (size_t)(rr * 4 + hi) * NSEQ + tz * 64 + l15 * 4));
        }
    }

    // ---------------- pass 2: probs + PV ----------------
    STAGE_K(t0, kbuf[0]);
    STAGE_V(t0, vbuf[0]);
    __syncthreads();
    f32x4 accO[4];
    #pragma unroll
    for (int db = 0; db < 4; ++db) accO[db] = (f32x4){0.f, 0.f, 0.f, 0.f};

    cur = 0; t = t0;
    while (t < NT) {
        int tn = t + 1;
        while (tn < NT && !((amask >> tn) & 1u)) ++tn;
        if (tn < NT) {
            STAGE_K(tn, kbuf[cur ^ 1]);
            STAGE_V(tn, vbuf[cur ^ 1]);
        }
        f32x4 accS[4];
        #pragma unroll
        for (int cb = 0; cb < 4; ++cb) accS[cb] = (f32x4){0.f, 0.f, 0.f, 0.f};
        #pragma unroll
        for (int cb = 0; cb < 4; ++cb) {
            const int row = cb * 16 + l15;
            const char* bp = (const char*)&kbuf[cur][0] + row * 128;
            const bf16x8 b0 = *(const bf16x8*)(bp + ((hi ^ (row & 7)) * 16));
            const bf16x8 b1 = *(const bf16x8*)(bp + (((4 + hi) ^ (row & 7)) * 16));
            accS[cb] = MFMA16(aq0, b0, accS[cb]);
            accS[cb] = MFMA16(aq1, b1, accS[cb]);
        }

        // probs: non-temporal attn store from registers + swizzled bf16 P
        {
            float* abase = attn + ((size_t)bh * NSEQ + q0 + w * 16) * NSEQ + t * 64;
            #pragma unroll
            for (int cb = 0; cb < 4; ++cb)
                #pragma unroll
                for (int r = 0; r < 4; ++r) {
                    const int prow = hi * 4 + r;
                    const float p = __expf(accS[cb][r]) * rl[r];
                    __builtin_nontemporal_store(
                        p, abase + (size_t)prow * NSEQ + cb * 16 + l15);
                    const int col = cb * 16 + l15;
                    psh[(w * 16 + prow) * 64 +
                        (((col >> 3) ^ (prow & 7)) << 3) + (col & 7)] = f2bf(p);
                }
        }

        // PV MFMA: A = bf16 P slice (swizzled read), B = V^T tile
        #pragma unroll
        for (int s = 0; s < 2; ++s) {
            const bf16x8 pa = *(const bf16x8*)
                &psh[(w * 16 + l15) * 64 + (((s * 4 + hi) ^ (l15 & 7)) << 3)];
            #pragma unroll
            for (int db = 0; db < 4; ++db) {
                const int row = db * 16 + l15;
                const char* bp = (const char*)&vbuf[cur][0] + row * 128;
                const bf16x8 bv = *(const bf16x8*)(bp + (((4 * s + hi) ^ (row & 7)) * 16));
                accO[db] = MFMA16(pa, bv, accO[db]);
            }
        }
        __syncthreads();
        cur ^= 1; t = tn;
    }

    // epilogue: accO -> psh (bf16, swizzled) -> outh
    // (outh's XOR absorbed: physical block pb holds logical pb^(n&7))
    #pragma unroll
    for (int db = 0; db < 4; ++db)
        #pragma unroll
        for (int r = 0; r < 4; ++r) {
            const int prow = hi * 4 + r;
            const int col = db * 16 + l15;
            psh[(w * 16 + prow) * 64 +
                (((col >> 3) ^ (prow & 7)) << 3) + (col & 7)] = f2bf(accO[db][r]);
        }
    // per-wave slice, same-wave in-order: no barrier needed
    #pragma unroll
    for (int i = 0; i < 2; ++i) {
        const int u = lane + i * 64;
        const int rowL = u >> 3;
        const int blk = u & 7;
        const bf16x8 o = *(const bf16x8*)&psh[(w * 16 + rowL) * 64 + blk * 8];
        const int n = q0 + w * 16 + rowL;
        *(bf16x8*)(outh + ((size_t)(b * NSEQ + n)) * 512 + h * 64 + blk * 8) = o;
    }
    #undef STAGE_K
    #undef STAGE_V
}

// ---------------------------------------------------------------------------
extern "C" void kernel_launch(void* const* d_in, const int* in_sizes, int n_in,
                              void* d_out, int out_size, void* d_ws, size_t ws_size,
                              hipStream_t stream)
{
    const float* x      = (const float*)d_in[0];
    const int*   mask   = (const int*)  d_in[1];
    const float* W_qkv  = (const float*)d_in[2];
    const float* W_proj = (const float*)d_in[3];
    const float* b_proj = (const float*)d_in[4];

    float* out  = (float*)d_out;
    float* attn = out + (size_t)BATCH * NSEQ * CDIM;

    char* ws = (char*)d_ws;
    unsigned short* qkb  = (unsigned short*)ws;                          // 10.49 MB (5120x1024)
    unsigned short* Vtf  = qkb + (size_t)5120 * 1024;                    //  5.24 MB (512x5120)
    unsigned short* xb   = Vtf + (size_t)512 * 5120;                     //  5.24 MB
    unsigned short* Wqt  = xb + (size_t)5120 * 512;                      //  1.57 MB
    unsigned short* Wpt  = Wqt + (size_t)1536 * 512;                     //  0.52 MB
    unsigned short* outh = Wpt + (size_t)512 * 512;                      //  5.24 MB (28.3 total)

    const int M = BATCH * NSEQ;   // 5120

    // 0) convert: x -> bf16 (swizzled), weights -> transposed bf16
    conv_kernel<<<1536, 256, 0, stream>>>(x, W_qkv, W_proj, xb, Wqt, Wpt);

    // 1) qkv = x @ Wqkv^T: Q/K -> qkb (stride 1024), V -> Vtf transposed.
    //    128x128 tiles, XCD-swz, 480 blocks.
    gemm_bf16<64, 64, false, true, true><<<480, 256, 0, stream>>>(
        xb, Wqt, nullptr, qkb, Vtf, M, 1536, 512, 1024);

    // 2) two-pass masked MFMA attention, QB=64, bh-XCD-pinned
    attn_mfma<<<BATCH * HEADS * NQT, 256, 0, stream>>>(qkb, Vtf, mask, attn, outh);

    // 3) out = outh @ Wp^T + b_proj (f32 out, nt), 64x128 tiles, XCD-swz
    gemm_bf16<32, 64, true, false, false><<<320, 256, 0, stream>>>(
        outh, Wpt, b_proj, out, nullptr, M, 512, 512, 512);
}

// Round 12
// 86.520 us; speedup vs baseline: 1.2161x; 1.2161x over previous
//
#include <hip/hip_runtime.h>
#include <math.h>

#define BATCH 4
#define NSEQ  1280
#define CDIM  512
#define HEADS 8
#define HD    64
#define NT    20     // 1280/64 k-tiles
#define NQT   20     // 1280/64 q-tiles (QB=64)

typedef __attribute__((ext_vector_type(8))) short bf16x8;
typedef __attribute__((ext_vector_type(4))) float f32x4;
typedef __attribute__((ext_vector_type(4))) unsigned short us4;

#define MFMA16(a,b,c) __builtin_amdgcn_mfma_f32_16x16x32_bf16(a,b,c,0,0,0)

__device__ __forceinline__ unsigned short f2bf(float f) {
    union { float f; unsigned int u; } v; v.f = f;
    unsigned int r = v.u + 0x7fffu + ((v.u >> 16) & 1u);   // RNE
    return (unsigned short)(r >> 16);
}
__device__ __forceinline__ float bf2f(unsigned short h) {
    union { unsigned int u; float f; } v; v.u = ((unsigned int)h) << 16;
    return v.f;
}
__device__ __forceinline__ void gload_lds16(const void* g, void* l) {
    __builtin_amdgcn_global_load_lds(
        (const __attribute__((address_space(1))) unsigned int*)g,
        (__attribute__((address_space(3))) unsigned int*)l, 16, 0, 0);
}

// ---------------------------------------------------------------------------
// conv: x f32 -> xb bf16 (5120 x 512, gemm-A swizzled)
//       W_qkv/W_proj f32 -> transposed bf16 (N x 512, gemm-B swizzled)
//       Q-columns of W_qkv (n<512) pre-scaled by 0.125 (folds attn scale)
// ---------------------------------------------------------------------------
__global__ __launch_bounds__(256)
void conv_kernel(const float* __restrict__ x, const float* __restrict__ Wq,
                 const float* __restrict__ Wp, unsigned short* __restrict__ xb,
                 unsigned short* __restrict__ Wqt, unsigned short* __restrict__ Wpt)
{
    __shared__ float lt[64][65];
    const int bx = blockIdx.x;
    const int tid = threadIdx.x;
    if (bx < 1280) {
        const int u = bx * 256 + tid;      // 5120 rows x 64 8-blocks
        const int m = u >> 6;
        const int b6 = u & 63;
        const int chunk = b6 >> 3;         // 64-elem K-chunk 0..7
        const int blk = b6 & 7;
        const float* src = x + (size_t)m * 512 + b6 * 8;
        bf16x8 hv;
        #pragma unroll
        for (int j = 0; j < 8; ++j) hv[j] = (short)f2bf(src[j]);
        *(bf16x8*)(xb + (size_t)m * 512 + chunk * 64 + ((blk ^ (m & 7)) * 8)) = hv;
    } else {
        int wi = bx - 1280;
        const float* W; unsigned short* Wt; int N, kt, nt; bool isQ;
        if (wi < 192) { W = Wq; Wt = Wqt; N = 1536; kt = wi / 24; nt = wi % 24; isQ = true; }
        else { wi -= 192; W = Wp; Wt = Wpt; N = 512; kt = wi / 8; nt = wi % 8; isQ = false; }
        const int k0 = kt * 64, n0 = nt * 64;
        {
            const int r = tid >> 4;
            const int c = (tid & 15) * 4;
            #pragma unroll
            for (int i = 0; i < 4; ++i) {
                const float4 v = *(const float4*)(W + (size_t)(k0 + r + i * 16) * N + n0 + c);
                lt[r + i * 16][c + 0] = v.x; lt[r + i * 16][c + 1] = v.y;
                lt[r + i * 16][c + 2] = v.z; lt[r + i * 16][c + 3] = v.w;
            }
        }
        __syncthreads();
        #pragma unroll
        for (int i = 0; i < 2; ++i) {
            const int u = tid + i * 256;
            const int n = u >> 3;
            const int blk = u & 7;
            const int kin = (blk ^ (n & 7)) * 8;
            const float sc = (isQ && (n0 + n) < 512) ? 0.125f : 1.0f;
            bf16x8 o;
            #pragma unroll
            for (int j = 0; j < 8; ++j) o[j] = (short)f2bf(lt[kin + j][n] * sc);
            *(bf16x8*)(Wt + (size_t)(n0 + n) * 512 + k0 + blk * 8) = o;
        }
    }
}

// ---------------------------------------------------------------------------
// bf16 MFMA GEMM: C(MxN) = A(M x 512, swz) @ B(N x 512, swz)^T
// 1D grid + XCD-chunked swizzle. SPLITV: n0>=1024 blocks (V columns) write
// C^T to Vtf[d][m] via padded-LDS transpose; n0<1024 writes qkb stride CN.
// ---------------------------------------------------------------------------
template<int WM, int WN, bool BIAS, bool OUTBF16, bool SPLITV>
__global__ __launch_bounds__(256)
void gemm_bf16(const unsigned short* __restrict__ A,
               const unsigned short* __restrict__ B,
               const float* __restrict__ bias, void* __restrict__ Cv,
               unsigned short* __restrict__ Vtf,
               int M, int N, int KA, int CN)
{
    constexpr int BM = 2 * WM, BN = 2 * WN;
    constexpr int MI = WM / 16, NI = WN / 16;
    constexpr int SM0 = (BM + BN) * 64;
    constexpr int SM1 = SPLITV ? BN * (BM + 8) : 0;
    __shared__ __align__(16) unsigned short smem[SM0 > SM1 ? SM0 : SM1];
    unsigned short* As = smem;
    unsigned short* Bs = smem + BM * 64;

    const int tid = threadIdx.x;
    const int w = tid >> 6, lane = tid & 63;
    const int l15 = lane & 15, hi = lane >> 4;
    const int wr = w >> 1, wc = w & 1;

    // XCD-chunked bijective swizzle (grid %8 == 0)
    const int nb = gridDim.x;
    const int L = (blockIdx.x & 7) * (nb >> 3) + (blockIdx.x >> 3);
    const int nx = N / BN;
    const int m0 = (L / nx) * BM, n0 = (L % nx) * BN;

    f32x4 acc[MI][NI];
    #pragma unroll
    for (int mi = 0; mi < MI; ++mi)
        #pragma unroll
        for (int ni = 0; ni < NI; ++ni) acc[mi][ni] = (f32x4){0.f, 0.f, 0.f, 0.f};

    constexpr int LA = BM * 128 / 4096;
    constexpr int LB = BN * 128 / 4096;

    for (int k0 = 0; k0 < KA; k0 += 64) {
        #pragma unroll
        for (int i = 0; i < LA; ++i) {
            const int off = tid * 16 + i * 4096;
            const int row = off >> 7, cb = off & 127;
            gload_lds16((const char*)A + ((size_t)(m0 + row) * KA + k0) * 2 + cb,
                        (char*)As + off);
        }
        #pragma unroll
        for (int i = 0; i < LB; ++i) {
            const int off = tid * 16 + i * 4096;
            const int row = off >> 7, cb = off & 127;
            gload_lds16((const char*)B + ((size_t)(n0 + row) * 512 + k0) * 2 + cb,
                        (char*)Bs + off);
        }
        __syncthreads();
        #pragma unroll
        for (int kk = 0; kk < 2; ++kk) {
            bf16x8 af[MI], bfr[NI];
            #pragma unroll
            for (int mi = 0; mi < MI; ++mi) {
                const int row = wr * WM + mi * 16 + l15;
                af[mi] = *(const bf16x8*)(As + row * 64 + ((kk * 4 + hi) ^ (row & 7)) * 8);
            }
            #pragma unroll
            for (int ni = 0; ni < NI; ++ni) {
                const int row = wc * WN + ni * 16 + l15;
                bfr[ni] = *(const bf16x8*)(Bs + row * 64 + ((kk * 4 + hi) ^ (row & 7)) * 8);
            }
            #pragma unroll
            for (int mi = 0; mi < MI; ++mi)
                #pragma unroll
                for (int ni = 0; ni < NI; ++ni)
                    acc[mi][ni] = MFMA16(af[mi], bfr[ni], acc[mi][ni]);
        }
        __syncthreads();
    }

    if (SPLITV && n0 >= 1024) {
        // V columns: write C^T (bf16) -> Vtf[d = n0-1024+col][m0+row], linear
        #pragma unroll
        for (int mi = 0; mi < MI; ++mi)
            #pragma unroll
            for (int ni = 0; ni < NI; ++ni) {
                us4 tv;
                tv[0] = f2bf(acc[mi][ni][0]); tv[1] = f2bf(acc[mi][ni][1]);
                tv[2] = f2bf(acc[mi][ni][2]); tv[3] = f2bf(acc[mi][ni][3]);
                const int col = wc * WN + ni * 16 + l15;
                *(us4*)&smem[col * (BM + 8) + wr * WM + mi * 16 + hi * 4] = tv;
            }
        __syncthreads();
        constexpr int UNITS2 = BN * (BM / 8) / 256;
        #pragma unroll
        for (int i = 0; i < UNITS2; ++i) {
            const int u = tid + i * 256;
            const int srow = u / (BM / 8), cu = u % (BM / 8);
            *(bf16x8*)(Vtf + (size_t)(n0 - 1024 + srow) * 5120 + m0 + cu * 8) =
                *(const bf16x8*)&smem[srow * (BM + 8) + cu * 8];
        }
    } else if (OUTBF16) {
        unsigned short* C = (unsigned short*)Cv;
        #pragma unroll
        for (int mi = 0; mi < MI; ++mi)
            #pragma unroll
            for (int ni = 0; ni < NI; ++ni)
                #pragma unroll
                for (int r = 0; r < 4; ++r)
                    smem[(wr * WM + mi * 16 + hi * 4 + r) * BN + wc * WN + ni * 16 + l15] =
                        f2bf(acc[mi][ni][r]);
        __syncthreads();
        constexpr int UNITS = BM * BN / 8 / 256;
        #pragma unroll
        for (int i = 0; i < UNITS; ++i) {
            const int u = tid + i * 256;
            const int row = u / (BN / 8), cb = u % (BN / 8);
            *(bf16x8*)(C + (size_t)(m0 + row) * CN + n0 + cb * 8) =
                *(const bf16x8*)(smem + row * BN + cb * 8);
        }
    } else {
        float* C = (float*)Cv;
        #pragma unroll
        for (int mi = 0; mi < MI; ++mi)
            #pragma unroll
            for (int ni = 0; ni < NI; ++ni) {
                const int col = n0 + wc * WN + ni * 16 + l15;
                const float bv = BIAS ? bias[col] : 0.f;
                #pragma unroll
                for (int r = 0; r < 4; ++r)
                    C[(size_t)(m0 + wr * WM + mi * 16 + hi * 4 + r) * CN + col] =
                        acc[mi][ni][r] + bv;
            }
    }
}

// ---------------------------------------------------------------------------
// Two-pass MFMA attention, QB=64, Q/K from qkb (5120x1024), V from Vtf.
// Round-10 store path (regular stores). psh = flat XOR-swizzled 8KB ->
// block LDS exactly 40960B = 4 blocks/CU (occupancy lever).
// outh's global XOR absorbed into psh swizzle (n&7 == rowL&7).
// XCD swizzle: bh = bx % 32 -> all 20 q-tiles of a (b,h) share one XCD L2.
// ---------------------------------------------------------------------------
__global__ __launch_bounds__(256)
void attn_mfma(const unsigned short* __restrict__ qkb,
               const unsigned short* __restrict__ Vtf,
               const int* __restrict__ mask,
               float* __restrict__ attn, unsigned short* __restrict__ outh)
{
    __shared__ __align__(16) unsigned short kbuf[2][4096];
    __shared__ __align__(16) unsigned short vbuf[2][4096];
    __shared__ __align__(16) unsigned short psh[4096];   // 64x64 bf16, XOR-swizzled

    const int bx = blockIdx.x;
    const int bh = bx & 31;           // XCD = bh % 8
    const int qt = bx >> 5;
    const int b = bh >> 3, h = bh & 7;
    const int tid = threadIdx.x;
    const int w = tid >> 6;
    const int lane = tid & 63;
    const int l15 = lane & 15;
    const int hi = lane >> 4;
    const int q0 = qt * 64;

    unsigned int amask = 0xF0000u;
    #pragma unroll
    for (int g = 0; g < 4; ++g)
        if (mask[b * 4 + g] != 0) amask |= (0xFu << (g * 4));

    // Q fragments directly from qkb (pre-scaled by 1/8 via Wqt)
    const unsigned short* qrow =
        qkb + (size_t)(b * NSEQ + q0 + w * 16 + l15) * 1024 + h * HD;
    const bf16x8 aq0 = *(const bf16x8*)(qrow + hi * 8);
    const bf16x8 aq1 = *(const bf16x8*)(qrow + 32 + hi * 8);

    const unsigned short* ks = qkb + (size_t)b * NSEQ * 1024 + 512 + h * HD;
    const unsigned short* vg = Vtf + (size_t)h * HD * 5120 + b * NSEQ;

    // stage K tile t (source-swizzled rows of qkb) / V tile t (source-swz Vtf)
    #define STAGE_K(t, buf)                                                      \
        { _Pragma("unroll")                                                      \
          for (int half_ = 0; half_ < 2; ++half_) {                              \
            const int idx_ = half_ * 256 + tid;                                  \
            const int row_ = idx_ >> 3, blk_ = idx_ & 7;                         \
            gload_lds16(ks + (size_t)((t) * 64 + row_) * 1024                    \
                           + ((blk_ ^ (row_ & 7)) * 8),                          \
                        (char*)&(buf)[0] + idx_ * 16); } }
    #define STAGE_V(t, buf)                                                      \
        { _Pragma("unroll")                                                      \
          for (int half_ = 0; half_ < 2; ++half_) {                              \
            const int idx_ = half_ * 256 + tid;                                  \
            const int row_ = idx_ >> 3, blk_ = idx_ & 7;                         \
            gload_lds16(vg + (size_t)row_ * 5120 + (t) * 64                      \
                           + ((blk_ ^ (row_ & 7)) * 8),                          \
                        (char*)&(buf)[0] + idx_ * 16); } }

    float lr[4] = {0.f, 0.f, 0.f, 0.f};

    int t0 = 0;
    while (!((amask >> t0) & 1u)) ++t0;

    // ---------------- pass 1: exp-sums (fixed max = 0) ----------------
    STAGE_K(t0, kbuf[0]);
    __syncthreads();
    int cur = 0, t = t0;
    while (t < NT) {
        int tn = t + 1;
        while (tn < NT && !((amask >> tn) & 1u)) ++tn;
        if (tn < NT) STAGE_K(tn, kbuf[cur ^ 1]);
        f32x4 accS[4];
        #pragma unroll
        for (int cb = 0; cb < 4; ++cb) accS[cb] = (f32x4){0.f, 0.f, 0.f, 0.f};
        #pragma unroll
        for (int cb = 0; cb < 4; ++cb) {
            const int row = cb * 16 + l15;
            const char* bp = (const char*)&kbuf[cur][0] + row * 128;
            const bf16x8 b0 = *(const bf16x8*)(bp + ((hi ^ (row & 7)) * 16));
            const bf16x8 b1 = *(const bf16x8*)(bp + (((4 + hi) ^ (row & 7)) * 16));
            accS[cb] = MFMA16(aq0, b0, accS[cb]);
            accS[cb] = MFMA16(aq1, b1, accS[cb]);
        }
        #pragma unroll
        for (int cb = 0; cb < 4; ++cb)
            #pragma unroll
            for (int r = 0; r < 4; ++r)
                lr[r] += __expf(accS[cb][r]);
        __syncthreads();
        cur ^= 1; t = tn;
    }

    float rl[4];
    #pragma unroll
    for (int r = 0; r < 4; ++r) {
        float s = lr[r];
        s += __shfl_xor(s, 1);
        s += __shfl_xor(s, 2);
        s += __shfl_xor(s, 4);
        s += __shfl_xor(s, 8);
        rl[r] = 1.f / s;
    }

    // zero-fill masked tiles of attn
    {
        float* arow = attn + ((size_t)bh * NSEQ + q0 + w * 16) * NSEQ;
        const float4 z = make_float4(0.f, 0.f, 0.f, 0.f);
        for (int tz = 0; tz < NT; ++tz) {
            if ((amask >> tz) & 1u) continue;
            #pragma unroll
            for (int rr = 0; rr < 4; ++rr)
                *(float4*)(arow + (size_t)(rr * 4 + hi) * NSEQ + tz * 64 + l15 * 4) = z;
        }
    }

    // ---------------- pass 2: probs + PV ----------------
    STAGE_K(t0, kbuf[0]);
    STAGE_V(t0, vbuf[0]);
    __syncthreads();
    f32x4 accO[4];
    #pragma unroll
    for (int db = 0; db < 4; ++db) accO[db] = (f32x4){0.f, 0.f, 0.f, 0.f};

    cur = 0; t = t0;
    while (t < NT) {
        int tn = t + 1;
        while (tn < NT && !((amask >> tn) & 1u)) ++tn;
        if (tn < NT) {
            STAGE_K(tn, kbuf[cur ^ 1]);
            STAGE_V(tn, vbuf[cur ^ 1]);
        }
        f32x4 accS[4];
        #pragma unroll
        for (int cb = 0; cb < 4; ++cb) accS[cb] = (f32x4){0.f, 0.f, 0.f, 0.f};
        #pragma unroll
        for (int cb = 0; cb < 4; ++cb) {
            const int row = cb * 16 + l15;
            const char* bp = (const char*)&kbuf[cur][0] + row * 128;
            const bf16x8 b0 = *(const bf16x8*)(bp + ((hi ^ (row & 7)) * 16));
            const bf16x8 b1 = *(const bf16x8*)(bp + (((4 + hi) ^ (row & 7)) * 16));
            accS[cb] = MFMA16(aq0, b0, accS[cb]);
            accS[cb] = MFMA16(aq1, b1, accS[cb]);
        }

        // probs: direct attn store from registers + swizzled bf16 P into psh
        {
            float* abase = attn + ((size_t)bh * NSEQ + q0 + w * 16) * NSEQ + t * 64;
            #pragma unroll
            for (int cb = 0; cb < 4; ++cb)
                #pragma unroll
                for (int r = 0; r < 4; ++r) {
                    const int prow = hi * 4 + r;
                    const float p = __expf(accS[cb][r]) * rl[r];
                    abase[(size_t)prow * NSEQ + cb * 16 + l15] = p;
                    const int col = cb * 16 + l15;
                    psh[(w * 16 + prow) * 64 +
                        (((col >> 3) ^ (prow & 7)) << 3) + (col & 7)] = f2bf(p);
                }
        }

        // PV MFMA: A = bf16 P slice (swizzled read), B = V^T tile
        #pragma unroll
        for (int s = 0; s < 2; ++s) {
            const bf16x8 pa = *(const bf16x8*)
                &psh[(w * 16 + l15) * 64 + (((s * 4 + hi) ^ (l15 & 7)) << 3)];
            #pragma unroll
            for (int db = 0; db < 4; ++db) {
                const int row = db * 16 + l15;
                const char* bp = (const char*)&vbuf[cur][0] + row * 128;
                const bf16x8 bv = *(const bf16x8*)(bp + (((4 * s + hi) ^ (row & 7)) * 16));
                accO[db] = MFMA16(pa, bv, accO[db]);
            }
        }
        __syncthreads();
        cur ^= 1; t = tn;
    }

    // epilogue: accO -> psh (bf16, swizzled) -> outh
    // (outh's XOR absorbed: physical block pb holds logical pb^(n&7))
    #pragma unroll
    for (int db = 0; db < 4; ++db)
        #pragma unroll
        for (int r = 0; r < 4; ++r) {
            const int prow = hi * 4 + r;
            const int col = db * 16 + l15;
            psh[(w * 16 + prow) * 64 +
                (((col >> 3) ^ (prow & 7)) << 3) + (col & 7)] = f2bf(accO[db][r]);
        }
    // per-wave slice, same-wave in-order: no barrier needed
    #pragma unroll
    for (int i = 0; i < 2; ++i) {
        const int u = lane + i * 64;
        const int rowL = u >> 3;
        const int blk = u & 7;
        const bf16x8 o = *(const bf16x8*)&psh[(w * 16 + rowL) * 64 + blk * 8];
        const int n = q0 + w * 16 + rowL;
        *(bf16x8*)(outh + ((size_t)(b * NSEQ + n)) * 512 + h * 64 + blk * 8) = o;
    }
    #undef STAGE_K
    #undef STAGE_V
}

// ---------------------------------------------------------------------------
extern "C" void kernel_launch(void* const* d_in, const int* in_sizes, int n_in,
                              void* d_out, int out_size, void* d_ws, size_t ws_size,
                              hipStream_t stream)
{
    const float* x      = (const float*)d_in[0];
    const int*   mask   = (const int*)  d_in[1];
    const float* W_qkv  = (const float*)d_in[2];
    const float* W_proj = (const float*)d_in[3];
    const float* b_proj = (const float*)d_in[4];

    float* out  = (float*)d_out;
    float* attn = out + (size_t)BATCH * NSEQ * CDIM;

    char* ws = (char*)d_ws;
    unsigned short* qkb  = (unsigned short*)ws;                          // 10.49 MB (5120x1024)
    unsigned short* Vtf  = qkb + (size_t)5120 * 1024;                    //  5.24 MB (512x5120)
    unsigned short* xb   = Vtf + (size_t)512 * 5120;                     //  5.24 MB
    unsigned short* Wqt  = xb + (size_t)5120 * 512;                      //  1.57 MB
    unsigned short* Wpt  = Wqt + (size_t)1536 * 512;                     //  0.52 MB
    unsigned short* outh = Wpt + (size_t)512 * 512;                      //  5.24 MB (28.3 total)

    const int M = BATCH * NSEQ;   // 5120

    // 0) convert: x -> bf16 (swizzled), weights -> transposed bf16
    conv_kernel<<<1536, 256, 0, stream>>>(x, W_qkv, W_proj, xb, Wqt, Wpt);

    // 1) qkv = x @ Wqkv^T: Q/K -> qkb (stride 1024), V -> Vtf transposed.
    //    128x128 tiles, XCD-swz, 480 blocks.
    gemm_bf16<64, 64, false, true, true><<<480, 256, 0, stream>>>(
        xb, Wqt, nullptr, qkb, Vtf, M, 1536, 512, 1024);

    // 2) two-pass masked MFMA attention, QB=64, bh-XCD-pinned
    attn_mfma<<<BATCH * HEADS * NQT, 256, 0, stream>>>(qkb, Vtf, mask, attn, outh);

    // 3) out = outh @ Wp^T + b_proj (f32 out), 64x128 tiles, XCD-swz
    gemm_bf16<32, 64, true, false, false><<<320, 256, 0, stream>>>(
        outh, Wpt, b_proj, out, nullptr, M, 512, 512, 512);
}